// Round 3
// baseline (22938.692 us; speedup 1.0000x reference)
//
#include <hip/hip_runtime.h>
#include <stdint.h>
#include <stddef.h>

// TPGRUCell forward, MI355X gfx950.
// Inputs: float32 (per reference). Output: FLOAT32 (reference output dtype).
// Phase 1: 5 MFMA GEMMs (f32 operands converted to bf16 during LDS staging).
// Phase 2: 512 sequential steps, 2 launches each (stage A GEMM, fused stage B+C),
//          operating on bf16 ws copies of the 5 recurrent weights.
// h master state kept in f32; bf16 only at MFMA operand boundaries.

#define T_LEN 512
#define BATCH 64
#define DIN   512
#define DH    512
#define DT    128

typedef __attribute__((ext_vector_type(8))) short short8;
typedef __attribute__((ext_vector_type(4))) float f32x4;

static __device__ __forceinline__ float bf2f(unsigned short u) {
  unsigned v = ((unsigned)u) << 16;
  return __builtin_bit_cast(float, v);
}
static __device__ __forceinline__ unsigned short f2bf(float f) {
  unsigned v = __builtin_bit_cast(unsigned, f);
  unsigned r = (v + 0x7fffu + ((v >> 16) & 1u)) >> 16;
  return (unsigned short)r;
}
static __device__ __forceinline__ float sigmoid_f(float x) {
  return 1.f / (1.f + __expf(-x));
}
static __device__ __forceinline__ float tanh_f(float x) {
  float e = __expf(-2.f * fabsf(x));
  float t = (1.f - e) / (1.f + e);
  return copysignf(t, x);
}

// Load 8 consecutive elements (along k / along n) as bf16, converting if f32.
template<bool F32>
static __device__ __forceinline__ void load8(const void* p, size_t off, unsigned short* d) {
  if (F32) {
    const float4* q = (const float4*)((const float*)p + off);
    float4 a = q[0], b = q[1];
    d[0] = f2bf(a.x); d[1] = f2bf(a.y); d[2] = f2bf(a.z); d[3] = f2bf(a.w);
    d[4] = f2bf(b.x); d[5] = f2bf(b.y); d[6] = f2bf(b.z); d[7] = f2bf(b.w);
  } else {
    *(uint4*)d = *(const uint4*)((const unsigned short*)p + off);
  }
}

// ---------------------------------------------------------------------------
// k_cvt: flat f32 -> bf16 copy (n multiple of 4)
// ---------------------------------------------------------------------------
__global__ __launch_bounds__(256) void k_cvt(const float* __restrict__ src,
                                             unsigned short* __restrict__ dst, int n) {
  int i = (blockIdx.x * 256 + threadIdx.x) * 4;
  if (i < n) {
    float4 v = *(const float4*)(src + i);
    unsigned short o[4] = { f2bf(v.x), f2bf(v.y), f2bf(v.z), f2bf(v.w) };
    *(uint2*)(dst + i) = *(const uint2*)o;
  }
}

// ---------------------------------------------------------------------------
// k_topic: the four topic@W projections, all f32.
// ---------------------------------------------------------------------------
__global__ __launch_bounds__(256) void k_topic(
    const float* __restrict__ topic,
    const float* __restrict__ Wzx,  // [128][1024]
    const float* __restrict__ Wzh,  // [128][1024]
    const float* __restrict__ Whx,  // [128][512]
    const float* __restrict__ Whh,  // [128][512]
    float* __restrict__ tzx, float* __restrict__ tzh,
    float* __restrict__ thx, float* __restrict__ thh)
{
  const int b = blockIdx.x;
  __shared__ float tp[DT];
  if (threadIdx.x < DT) tp[threadIdx.x] = topic[b * DT + threadIdx.x];
  __syncthreads();
  for (int c = threadIdx.x; c < 3072; c += 256) {
    const float* wp; float* op; int ld, cc;
    if (c < 1024)      { wp = Wzx; ld = 1024; cc = c;        op = &tzx[b*1024 + cc]; }
    else if (c < 2048) { wp = Wzh; ld = 1024; cc = c - 1024; op = &tzh[b*1024 + cc]; }
    else if (c < 2560) { wp = Whx; ld = 512;  cc = c - 2048; op = &thx[b*512  + cc]; }
    else               { wp = Whh; ld = 512;  cc = c - 2560; op = &thh[b*512  + cc]; }
    float acc = 0.f;
    #pragma unroll 4
    for (int k = 0; k < DT; ++k) acc += tp[k] * wp[(size_t)k * ld + cc];
    *op = acc;
  }
}

// ---------------------------------------------------------------------------
// gemm64: C(bf16) = A @ B (KxN row-major), 64x64 block tile.
// A/B may each be f32 (converted during staging) or bf16.
// EPI==0: C *= rs[(row&63)*ldrs + col]   (tp scale; row%64 == batch index)
// EPI==1: C += bias[col]                 (bias f32)
// Concat: blocks with n0 >= nsplit use B2/rs2 (col index n0-nsplit).
// MFMA 16x16x32 bf16 fragment layouts (m89/m120 verified):
//   A: m=lane&15, k=(lane>>4)*8+j ; B: n=lane&15, k=(lane>>4)*8+j
//   C/D: col=lane&15, row=(lane>>4)*4+reg
// ---------------------------------------------------------------------------
template<int EPI, bool AF32, bool BF32>
__global__ __launch_bounds__(256) void gemm64(
    const void* __restrict__ A, int lda,
    const void* __restrict__ B1, int ldb1,
    const float* __restrict__ rs1, int ldrs1,
    const float* __restrict__ bias,
    unsigned short* __restrict__ C, int ldc, int K,
    const void* __restrict__ B2, int ldb2,
    const float* __restrict__ rs2, int ldrs2, int nsplit)
{
  __shared__ unsigned short As[64][48];  // [m][k], row stride 96B (16B aligned)
  __shared__ unsigned short Bs[64][48];  // transposed: [n][k]
  const int tid = threadIdx.x;
  const int n0 = blockIdx.x * 64;
  const int m0 = blockIdx.y * 64;
  const void* B = B1; int ldb = ldb1;
  const float* rs = rs1; int ldrs = ldrs1; int nb0 = n0;
  if (n0 >= nsplit) { B = B2; ldb = ldb2; rs = rs2; ldrs = ldrs2; nb0 = n0 - nsplit; }
  const int wv = tid >> 6, lane = tid & 63;
  const int lh = lane & 15, q8 = (lane >> 4) * 8;
  const int arow = tid >> 2, acol = (tid & 3) * 8;   // A tile 64x32, 8 elems/thread
  const int brow = tid >> 3, bcol = (tid & 7) * 8;   // B tile 32x64, 8 elems/thread
  f32x4 acc[4] = {{0,0,0,0},{0,0,0,0},{0,0,0,0},{0,0,0,0}};

  for (int k0 = 0; k0 < K; k0 += 32) {
    unsigned short av[8], bv[8];
    load8<AF32>(A, (size_t)(m0 + arow) * lda + (k0 + acol), av);
    load8<BF32>(B, (size_t)(k0 + brow) * ldb + (nb0 + bcol), bv);
    __syncthreads();   // previous iteration's fragment reads done
    *(uint4*)(&As[arow][acol]) = *(const uint4*)av;
    #pragma unroll
    for (int i = 0; i < 8; ++i) Bs[bcol + i][brow] = bv[i];
    __syncthreads();
    short8 af = *(const short8*)(&As[wv * 16 + lh][q8]);
    #pragma unroll
    for (int nt = 0; nt < 4; ++nt) {
      short8 bf = *(const short8*)(&Bs[nt * 16 + lh][q8]);
      acc[nt] = __builtin_amdgcn_mfma_f32_16x16x32_bf16(af, bf, acc[nt], 0, 0, 0);
    }
  }

  #pragma unroll
  for (int nt = 0; nt < 4; ++nt) {
    #pragma unroll
    for (int r = 0; r < 4; ++r) {
      int row = m0 + wv * 16 + (lane >> 4) * 4 + r;
      int colc = nt * 16 + lh;
      float v = acc[nt][r];
      if (EPI == 0) v *= rs[(size_t)(row & 63) * ldrs + (nb0 + colc)];
      else          v += bias[nb0 + colc];
      C[(size_t)row * ldc + (n0 + colc)] = f2bf(v);
    }
  }
}

// ---------------------------------------------------------------------------
// stepBC: stage B (3 GEMMs over stage-A outputs) + stage C (gates) fused.
// Block = 64 output cols (grid 8), 256 threads. MFMA operands bf16 (ws copies).
// Output written as FLOAT32.
// ---------------------------------------------------------------------------
__global__ __launch_bounds__(256) void stepBC(
    const unsigned short* __restrict__ ZH,    // [64][1536] bf16: [z_htp|r_htp|u]
    const unsigned short* __restrict__ Wz,    // [512][512] bf16
    const unsigned short* __restrict__ Wr,
    const unsigned short* __restrict__ Wv,
    const unsigned short* __restrict__ ZRx,   // [T*64][1024] bf16
    const unsigned short* __restrict__ Hx,    // [T*64][512] bf16
    float* __restrict__ Hst,                  // [64][512] f32 master h
    unsigned short* __restrict__ Hbf,         // [64][512] bf16 copy (stage A operand)
    const float* __restrict__ mask,           // [T*64] f32
    float* __restrict__ out,                  // d_out f32
    int t)
{
  __shared__ unsigned short Az[64][48], Ar[64][48], Av[64][48]; // [b][k]
  __shared__ unsigned short Bz[64][48], Br[64][48], Bv[64][48]; // [n][k]
  const int tid = threadIdx.x;
  const int c0 = blockIdx.x * 64;
  const int wv = tid >> 6, lane = tid & 63;
  const int lh = lane & 15, q8 = (lane >> 4) * 8;
  const int arow = tid >> 2, acol = (tid & 3) * 8;
  const int brow = tid >> 3, bcol = (tid & 7) * 8;
  f32x4 aZ[4] = {{0,0,0,0},{0,0,0,0},{0,0,0,0},{0,0,0,0}};
  f32x4 aR[4] = {{0,0,0,0},{0,0,0,0},{0,0,0,0},{0,0,0,0}};
  f32x4 aV[4] = {{0,0,0,0},{0,0,0,0},{0,0,0,0},{0,0,0,0}};

  for (int k0 = 0; k0 < 512; k0 += 32) {
    uint4 az = *(const uint4*)(ZH + (size_t)arow * 1536 +        (k0 + acol));
    uint4 ar = *(const uint4*)(ZH + (size_t)arow * 1536 + 512  + (k0 + acol));
    uint4 au = *(const uint4*)(ZH + (size_t)arow * 1536 + 1024 + (k0 + acol));
    uint4 bz = *(const uint4*)(Wz + (size_t)(k0 + brow) * 512 + c0 + bcol);
    uint4 br = *(const uint4*)(Wr + (size_t)(k0 + brow) * 512 + c0 + bcol);
    uint4 bu = *(const uint4*)(Wv + (size_t)(k0 + brow) * 512 + c0 + bcol);
    __syncthreads();
    *(uint4*)(&Az[arow][acol]) = az;
    *(uint4*)(&Ar[arow][acol]) = ar;
    *(uint4*)(&Av[arow][acol]) = au;
    const unsigned short* pz = (const unsigned short*)&bz;
    const unsigned short* pr = (const unsigned short*)&br;
    const unsigned short* pu = (const unsigned short*)&bu;
    #pragma unroll
    for (int i = 0; i < 8; ++i) {
      Bz[bcol + i][brow] = pz[i];
      Br[bcol + i][brow] = pr[i];
      Bv[bcol + i][brow] = pu[i];
    }
    __syncthreads();
    short8 fz = *(const short8*)(&Az[wv * 16 + lh][q8]);
    short8 fr = *(const short8*)(&Ar[wv * 16 + lh][q8]);
    short8 fu = *(const short8*)(&Av[wv * 16 + lh][q8]);
    #pragma unroll
    for (int nt = 0; nt < 4; ++nt) {
      short8 gz = *(const short8*)(&Bz[nt * 16 + lh][q8]);
      short8 gr = *(const short8*)(&Br[nt * 16 + lh][q8]);
      short8 gu = *(const short8*)(&Bv[nt * 16 + lh][q8]);
      aZ[nt] = __builtin_amdgcn_mfma_f32_16x16x32_bf16(fz, gz, aZ[nt], 0, 0, 0);
      aR[nt] = __builtin_amdgcn_mfma_f32_16x16x32_bf16(fr, gr, aR[nt], 0, 0, 0);
      aV[nt] = __builtin_amdgcn_mfma_f32_16x16x32_bf16(fu, gu, aV[nt], 0, 0, 0);
    }
  }

  #pragma unroll
  for (int nt = 0; nt < 4; ++nt) {
    #pragma unroll
    for (int r = 0; r < 4; ++r) {
      int b = wv * 16 + (lane >> 4) * 4 + r;
      int d = c0 + nt * 16 + lh;
      size_t itb = (size_t)t * BATCH + b;
      float pzv = aZ[nt][r] + bf2f(ZRx[itb * 1024 + d]);
      float prv = aR[nt][r] + bf2f(ZRx[itb * 1024 + 512 + d]);
      float z = sigmoid_f(pzv);
      float rr = sigmoid_f(prv);
      float hv = tanh_f(bf2f(Hx[itb * 512 + d]) + rr * aV[nt][r]);
      float hold = Hst[b * 512 + d];
      float m = mask[itb];
      float hnew = (1.f - z) * hv + z * hold;
      hnew = m * hnew + (1.f - m) * hold;
      Hst[b * 512 + d] = hnew;
      Hbf[b * 512 + d] = f2bf(hnew);
      out[itb * 512 + d] = hnew;
      if (t == T_LEN - 1) out[(size_t)T_LEN * BATCH * DH + (size_t)b * 512 + d] = hnew;
    }
  }
}

// ---------------------------------------------------------------------------
extern "C" void kernel_launch(void* const* d_in, const int* in_sizes, int n_in,
                              void* d_out, int out_size, void* d_ws, size_t ws_size,
                              hipStream_t stream) {
  (void)in_sizes; (void)n_in; (void)out_size; (void)ws_size;
  const float* x        = (const float*)d_in[0];
  const float* topic    = (const float*)d_in[1];
  const float* mask     = (const float*)d_in[2];
  const float* W_x2zr   = (const float*)d_in[3];
  const float* W_tp2zrx = (const float*)d_in[4];
  const float* W_xtp2z  = (const float*)d_in[5];
  const float* b_xtp2z  = (const float*)d_in[6];
  const float* W_xtp2r  = (const float*)d_in[7];
  const float* b_xtp2r  = (const float*)d_in[8];
  const float* W_h2zr   = (const float*)d_in[9];
  const float* W_tp2zrh = (const float*)d_in[10];
  const float* W_htp2z  = (const float*)d_in[11];
  const float* W_htp2r  = (const float*)d_in[12];
  const float* W_x2h    = (const float*)d_in[13];
  const float* W_tp2hx  = (const float*)d_in[14];
  const float* W_xtp2h  = (const float*)d_in[15];
  const float* b_xtp2h  = (const float*)d_in[16];
  const float* W_h2h    = (const float*)d_in[17];
  const float* W_tp2hh  = (const float*)d_in[18];
  const float* W_htp2h  = (const float*)d_in[19];
  float* out = (float*)d_out;

  // ---- workspace carve (~132 MB) ----
  char* w = (char*)d_ws;
  float* tzx = (float*)w;           w += (size_t)BATCH * 1024 * 4;   // 256 KB
  float* tzh = (float*)w;           w += (size_t)BATCH * 1024 * 4;   // 256 KB
  float* thx = (float*)w;           w += (size_t)BATCH * 512 * 4;    // 128 KB
  float* thh = (float*)w;           w += (size_t)BATCH * 512 * 4;    // 128 KB
  // bf16 copies of the 5 recurrent weights
  unsigned short* Wb_h2zr  = (unsigned short*)w; w += (size_t)512 * 1024 * 2; // 1 MB
  unsigned short* Wb_h2h   = (unsigned short*)w; w += (size_t)512 * 512 * 2;  // 512 KB
  unsigned short* Wb_htp2z = (unsigned short*)w; w += (size_t)512 * 512 * 2;
  unsigned short* Wb_htp2r = (unsigned short*)w; w += (size_t)512 * 512 * 2;
  unsigned short* Wb_htp2h = (unsigned short*)w; w += (size_t)512 * 512 * 2;
  unsigned short* ZRs   = (unsigned short*)w; w += (size_t)T_LEN * BATCH * 1024 * 2; // 64 MB
  unsigned short* ZRxtp = (unsigned short*)w; w += (size_t)T_LEN * BATCH * 1024 * 2; // 64 MB
  // Xhs/H_xtp alias the ZRs region (ZRs consumed before Xhs is written)
  unsigned short* Xhs  = ZRs;
  unsigned short* Hxtp = ZRs + (size_t)T_LEN * BATCH * 512;
  unsigned short* ZH   = (unsigned short*)w; w += (size_t)BATCH * 1536 * 2;  // 192 KB
  float*          Hst  = (float*)w;          w += (size_t)BATCH * 512 * 4;   // 128 KB
  unsigned short* Hbf  = (unsigned short*)w; w += (size_t)BATCH * 512 * 2;   // 64 KB

  const int M = T_LEN * BATCH;       // 32768
  const int NO_SPLIT = 1 << 30;

  // ---- weight conversions (recurrent weights -> bf16 ws copies) ----
  k_cvt<<<512 * 1024 / 1024, 256, 0, stream>>>(W_h2zr,  Wb_h2zr,  512 * 1024);
  k_cvt<<<512 * 512 / 1024, 256, 0, stream>>>(W_h2h,   Wb_h2h,   512 * 512);
  k_cvt<<<512 * 512 / 1024, 256, 0, stream>>>(W_htp2z, Wb_htp2z, 512 * 512);
  k_cvt<<<512 * 512 / 1024, 256, 0, stream>>>(W_htp2r, Wb_htp2r, 512 * 512);
  k_cvt<<<512 * 512 / 1024, 256, 0, stream>>>(W_htp2h, Wb_htp2h, 512 * 512);

  // ---- phase 1 ----
  k_topic<<<BATCH, 256, 0, stream>>>(topic, W_tp2zrx, W_tp2zrh, W_tp2hx, W_tp2hh,
                                     tzx, tzh, thx, thh);
  // ZRs = (x @ W_x2zr) * tzx[b]
  gemm64<0, true, true><<<dim3(1024/64, M/64), 256, 0, stream>>>(
      x, DIN, W_x2zr, 1024, tzx, 1024, nullptr, ZRs, 1024, DIN,
      nullptr, 0, nullptr, 0, NO_SPLIT);
  // ZRxtp[:, :512] = ZRs[:, :512] @ W_xtp2z + b_xtp2z
  gemm64<1, false, true><<<dim3(512/64, M/64), 256, 0, stream>>>(
      ZRs, 1024, W_xtp2z, 512, nullptr, 0, b_xtp2z, ZRxtp, 1024, 512,
      nullptr, 0, nullptr, 0, NO_SPLIT);
  // ZRxtp[:, 512:] = ZRs[:, 512:] @ W_xtp2r + b_xtp2r
  gemm64<1, false, true><<<dim3(512/64, M/64), 256, 0, stream>>>(
      ZRs + 512, 1024, W_xtp2r, 512, nullptr, 0, b_xtp2r, ZRxtp + 512, 1024, 512,
      nullptr, 0, nullptr, 0, NO_SPLIT);
  // Xhs = (x @ W_x2h) * thx[b]   (overwrites ZRs region — stream-ordered, safe)
  gemm64<0, true, true><<<dim3(512/64, M/64), 256, 0, stream>>>(
      x, DIN, W_x2h, 512, thx, 512, nullptr, Xhs, 512, DIN,
      nullptr, 0, nullptr, 0, NO_SPLIT);
  // Hxtp = Xhs @ W_xtp2h + b_xtp2h
  gemm64<1, false, true><<<dim3(512/64, M/64), 256, 0, stream>>>(
      Xhs, 512, W_xtp2h, 512, nullptr, 0, b_xtp2h, Hxtp, 512, 512,
      nullptr, 0, nullptr, 0, NO_SPLIT);

  // ---- phase 2: h0 = 0 ----
  hipMemsetAsync(Hst, 0, (size_t)BATCH * 512 * 4 + (size_t)BATCH * 512 * 2, stream);

  for (int t = 0; t < T_LEN; ++t) {
    // stage A: ZH = [ (h@W_h2zr)*tzh | (h@W_h2h)*thh ]   (M=64, N=1536, concat at 1024)
    gemm64<0, false, false><<<dim3(1536/64, 1), 256, 0, stream>>>(
        Hbf, 512, Wb_h2zr, 1024, tzh, 1024, nullptr, ZH, 1536, 512,
        Wb_h2h, 512, thh, 512, 1024);
    // stage B+C
    stepBC<<<dim3(512/64), 256, 0, stream>>>(
        ZH, Wb_htp2z, Wb_htp2r, Wb_htp2h, ZRxtp, Hxtp, Hst, Hbf, mask, out, t);
  }
}

// Round 4
// 16950.064 us; speedup vs baseline: 1.3533x; 1.3533x over previous
//
#include <hip/hip_runtime.h>
#include <stdint.h>
#include <stddef.h>

// TPGRUCell forward, MI355X gfx950.
// Inputs f32, output f32 (verified round 3: absmax 1.95e-3).
// Phase 1: 5 MFMA GEMMs (f32 staged->bf16). Phase 2: ONE persistent kernel,
// 32 WGs, own device-scope grid barrier, 512 steps x (stageA GEMM -> bar ->
// stageB GEMMs + gates -> bar). Weights pre-transposed [n][k] bf16 so MFMA
// fragments load straight from global (L2-hot) - no LDS in the hot loop.

#define T_LEN 512
#define BATCH 64
#define DIN   512
#define DH    512
#define DT    128
#define G_WGS 32

typedef __attribute__((ext_vector_type(8))) short short8;
typedef __attribute__((ext_vector_type(4))) float f32x4;

static __device__ __forceinline__ float bf2f(unsigned short u) {
  unsigned v = ((unsigned)u) << 16;
  return __builtin_bit_cast(float, v);
}
static __device__ __forceinline__ unsigned short f2bf(float f) {
  unsigned v = __builtin_bit_cast(unsigned, f);
  unsigned r = (v + 0x7fffu + ((v >> 16) & 1u)) >> 16;
  return (unsigned short)r;
}
static __device__ __forceinline__ float sigmoid_f(float x) {
  return 1.f / (1.f + __expf(-x));
}
static __device__ __forceinline__ float tanh_f(float x) {
  float e = __expf(-2.f * fabsf(x));
  float t = (1.f - e) / (1.f + e);
  return copysignf(t, x);
}

template<bool F32>
static __device__ __forceinline__ void load8(const void* p, size_t off, unsigned short* d) {
  if (F32) {
    const float4* q = (const float4*)((const float*)p + off);
    float4 a = q[0], b = q[1];
    d[0] = f2bf(a.x); d[1] = f2bf(a.y); d[2] = f2bf(a.z); d[3] = f2bf(a.w);
    d[4] = f2bf(b.x); d[5] = f2bf(b.y); d[6] = f2bf(b.z); d[7] = f2bf(b.w);
  } else {
    *(uint4*)d = *(const uint4*)((const unsigned short*)p + off);
  }
}

// ---------------------------------------------------------------------------
// k_tr: dst[n][k] (bf16) = src[k][n] (f32); K,N multiples of 32. LDS-tiled.
// ---------------------------------------------------------------------------
__global__ __launch_bounds__(256) void k_tr(const float* __restrict__ src,
                                            unsigned short* __restrict__ dst,
                                            int K, int N) {
  __shared__ float t[32][33];
  const int tx = threadIdx.x & 31, ty = threadIdx.x >> 5;  // 32 x 8
  const int k0 = blockIdx.y * 32, n0 = blockIdx.x * 32;
  for (int i = ty; i < 32; i += 8)
    t[i][tx] = src[(size_t)(k0 + i) * N + n0 + tx];
  __syncthreads();
  for (int i = ty; i < 32; i += 8)
    dst[(size_t)(n0 + i) * K + k0 + tx] = f2bf(t[tx][i]);
}

// ---------------------------------------------------------------------------
// k_topic: the four topic@W projections, all f32.
// ---------------------------------------------------------------------------
__global__ __launch_bounds__(256) void k_topic(
    const float* __restrict__ topic,
    const float* __restrict__ Wzx,  // [128][1024]
    const float* __restrict__ Wzh,  // [128][1024]
    const float* __restrict__ Whx,  // [128][512]
    const float* __restrict__ Whh,  // [128][512]
    float* __restrict__ tzx, float* __restrict__ tzh,
    float* __restrict__ thx, float* __restrict__ thh)
{
  const int b = blockIdx.x;
  __shared__ float tp[DT];
  if (threadIdx.x < DT) tp[threadIdx.x] = topic[b * DT + threadIdx.x];
  __syncthreads();
  for (int c = threadIdx.x; c < 3072; c += 256) {
    const float* wp; float* op; int ld, cc;
    if (c < 1024)      { wp = Wzx; ld = 1024; cc = c;        op = &tzx[b*1024 + cc]; }
    else if (c < 2048) { wp = Wzh; ld = 1024; cc = c - 1024; op = &tzh[b*1024 + cc]; }
    else if (c < 2560) { wp = Whx; ld = 512;  cc = c - 2048; op = &thx[b*512  + cc]; }
    else               { wp = Whh; ld = 512;  cc = c - 2560; op = &thh[b*512  + cc]; }
    float acc = 0.f;
    #pragma unroll 4
    for (int k = 0; k < DT; ++k) acc += tp[k] * wp[(size_t)k * ld + cc];
    *op = acc;
  }
}

// ---------------------------------------------------------------------------
// gemm64 (phase 1 only): C(bf16) = A @ B, 64x64 tile, LDS-staged.
// EPI==0: C *= rs[(row&63)*ldrs+col]; EPI==1: C += bias[col].
// ---------------------------------------------------------------------------
template<int EPI, bool AF32, bool BF32>
__global__ __launch_bounds__(256) void gemm64(
    const void* __restrict__ A, int lda,
    const void* __restrict__ B1, int ldb1,
    const float* __restrict__ rs1, int ldrs1,
    const float* __restrict__ bias,
    unsigned short* __restrict__ C, int ldc, int K)
{
  __shared__ unsigned short As[64][48];
  __shared__ unsigned short Bs[64][48];
  const int tid = threadIdx.x;
  const int n0 = blockIdx.x * 64;
  const int m0 = blockIdx.y * 64;
  const int wv = tid >> 6, lane = tid & 63;
  const int lh = lane & 15, q8 = (lane >> 4) * 8;
  const int arow = tid >> 2, acol = (tid & 3) * 8;
  const int brow = tid >> 3, bcol = (tid & 7) * 8;
  f32x4 acc[4] = {{0,0,0,0},{0,0,0,0},{0,0,0,0},{0,0,0,0}};

  for (int k0 = 0; k0 < K; k0 += 32) {
    unsigned short av[8], bv[8];
    load8<AF32>(A, (size_t)(m0 + arow) * lda + (k0 + acol), av);
    load8<BF32>(B1, (size_t)(k0 + brow) * ldb1 + (n0 + bcol), bv);
    __syncthreads();
    *(uint4*)(&As[arow][acol]) = *(const uint4*)av;
    #pragma unroll
    for (int i = 0; i < 8; ++i) Bs[bcol + i][brow] = bv[i];
    __syncthreads();
    short8 af = *(const short8*)(&As[wv * 16 + lh][q8]);
    #pragma unroll
    for (int nt = 0; nt < 4; ++nt) {
      short8 bf = *(const short8*)(&Bs[nt * 16 + lh][q8]);
      acc[nt] = __builtin_amdgcn_mfma_f32_16x16x32_bf16(af, bf, acc[nt], 0, 0, 0);
    }
  }

  #pragma unroll
  for (int nt = 0; nt < 4; ++nt) {
    #pragma unroll
    for (int r = 0; r < 4; ++r) {
      int row = m0 + wv * 16 + (lane >> 4) * 4 + r;
      int colc = nt * 16 + lh;
      float v = acc[nt][r];
      if (EPI == 0) v *= rs1[(size_t)(row & 63) * ldrs1 + (n0 + colc)];
      else          v += bias[n0 + colc];
      C[(size_t)row * ldc + (n0 + colc)] = f2bf(v);
    }
  }
}

// ---------------------------------------------------------------------------
// grid barrier: monotone-epoch counter, agent-scope fences around relaxed spin.
// ---------------------------------------------------------------------------
static __device__ __forceinline__ void gbar(int* bar, int target) {
  __syncthreads();      // all waves' stores issued & drained (waitcnt+barrier)
  __threadfence();      // agent release: flush XCD L2 to coherence point
  if (threadIdx.x == 0) {
    __hip_atomic_fetch_add(bar, 1, __ATOMIC_RELAXED, __HIP_MEMORY_SCOPE_AGENT);
    while (__hip_atomic_load(bar, __ATOMIC_RELAXED, __HIP_MEMORY_SCOPE_AGENT) < target)
      __builtin_amdgcn_s_sleep(1);
  }
  __syncthreads();
  __threadfence();      // agent acquire: invalidate stale L1/L2 before reads
}

// ---------------------------------------------------------------------------
// k_scan: persistent 512-step GRU scan. Grid = G_WGS x 256.
// Stage A: ZH[b][c] = (hbf @ WaT^T)[b][c] * scale,  c-slice 48 cols per WG.
// Stage B+C: 16 cols x 3 matrices per WG, fused gates; WG owns its h columns.
// Fragment layouts (m89-verified): A[m=lane&15][k=quad*8+j] from row-major,
// B[n=lane&15][k=quad*8+j] from [n][k]-transposed weights, C/D col=lane&15,
// row=quad*4+reg.
// ---------------------------------------------------------------------------
__global__ __launch_bounds__(256) void k_scan(
    const unsigned short* __restrict__ WaT,   // [1536][512] bf16 ([W_h2zr|W_h2h]^T)
    const unsigned short* __restrict__ WbT,   // [1536][512] bf16 (z|r|v stacked ^T)
    const float* __restrict__ tzh,            // [64][1024]
    const float* __restrict__ thh,            // [64][512]
    const unsigned short* __restrict__ ZRx,   // [T*64][1024] bf16
    const unsigned short* __restrict__ Hx,    // [T*64][512] bf16
    const float* __restrict__ mask,           // [T*64]
    unsigned short* ZH,                       // [64][1536] bf16 (rw, cross-WG)
    float* Hst,                               // [64][512] f32 master h
    unsigned short* hbf,                      // [64][512] bf16 (rw, cross-WG)
    float* out, int* bar)
{
  const int wg = blockIdx.x;
  const int tid = threadIdx.x;
  const int wv = tid >> 6, lane = tid & 63;
  const int lh = lane & 15, quad = lane >> 4;
  const int q8 = quad * 8;
  const int rowA = wv * 16 + lh;     // A-fragment row (batch)
  int ep = 0;

  for (int t = 0; t < T_LEN; ++t) {
    // ---- stage A ----
    f32x4 a0 = {0,0,0,0}, a1 = {0,0,0,0}, a2 = {0,0,0,0};
    #pragma unroll 4
    for (int k0 = 0; k0 < 512; k0 += 32) {
      short8 af = *(const short8*)(hbf + rowA * 512 + k0 + q8);
      short8 b0 = *(const short8*)(WaT + (size_t)(wg*48 +  0 + lh) * 512 + k0 + q8);
      short8 b1 = *(const short8*)(WaT + (size_t)(wg*48 + 16 + lh) * 512 + k0 + q8);
      short8 b2 = *(const short8*)(WaT + (size_t)(wg*48 + 32 + lh) * 512 + k0 + q8);
      a0 = __builtin_amdgcn_mfma_f32_16x16x32_bf16(af, b0, a0, 0, 0, 0);
      a1 = __builtin_amdgcn_mfma_f32_16x16x32_bf16(af, b1, a1, 0, 0, 0);
      a2 = __builtin_amdgcn_mfma_f32_16x16x32_bf16(af, b2, a2, 0, 0, 0);
    }
    {
      f32x4 av[3] = {a0, a1, a2};
      #pragma unroll
      for (int nt = 0; nt < 3; ++nt) {
        #pragma unroll
        for (int r = 0; r < 4; ++r) {
          int b = wv * 16 + quad * 4 + r;
          int c = wg * 48 + nt * 16 + lh;
          float sc = (c < 1024) ? tzh[b * 1024 + c] : thh[b * 512 + (c - 1024)];
          ZH[b * 1536 + c] = f2bf(av[nt][r] * sc);
        }
      }
    }
    ++ep; gbar(bar, ep * G_WGS);

    // ---- stage B + C ----
    f32x4 bz = {0,0,0,0}, br = {0,0,0,0}, bv = {0,0,0,0};
    #pragma unroll 4
    for (int k0 = 0; k0 < 512; k0 += 32) {
      const unsigned short* zrow = ZH + rowA * 1536;
      short8 az = *(const short8*)(zrow + k0 + q8);
      short8 ar = *(const short8*)(zrow + 512 + k0 + q8);
      short8 au = *(const short8*)(zrow + 1024 + k0 + q8);
      short8 wz = *(const short8*)(WbT + (size_t)(       wg*16 + lh) * 512 + k0 + q8);
      short8 wr = *(const short8*)(WbT + (size_t)(512  + wg*16 + lh) * 512 + k0 + q8);
      short8 wu = *(const short8*)(WbT + (size_t)(1024 + wg*16 + lh) * 512 + k0 + q8);
      bz = __builtin_amdgcn_mfma_f32_16x16x32_bf16(az, wz, bz, 0, 0, 0);
      br = __builtin_amdgcn_mfma_f32_16x16x32_bf16(ar, wr, br, 0, 0, 0);
      bv = __builtin_amdgcn_mfma_f32_16x16x32_bf16(au, wu, bv, 0, 0, 0);
    }
    #pragma unroll
    for (int r = 0; r < 4; ++r) {
      int b = wv * 16 + quad * 4 + r;
      int d = wg * 16 + lh;
      size_t itb = (size_t)t * BATCH + b;
      float pz = bz[r] + bf2f(ZRx[itb * 1024 + d]);
      float pr = br[r] + bf2f(ZRx[itb * 1024 + 512 + d]);
      float z  = sigmoid_f(pz);
      float rr = sigmoid_f(pr);
      float hv = tanh_f(bf2f(Hx[itb * 512 + d]) + rr * bv[r]);
      float hold = Hst[b * 512 + d];
      float m = mask[itb];
      float hnew = (1.f - z) * hv + z * hold;
      hnew = m * hnew + (1.f - m) * hold;
      Hst[b * 512 + d] = hnew;
      hbf[b * 512 + d] = f2bf(hnew);
      out[itb * 512 + d] = hnew;
      if (t == T_LEN - 1) out[(size_t)T_LEN * BATCH * DH + (size_t)b * 512 + d] = hnew;
    }
    ++ep; gbar(bar, ep * G_WGS);
  }
}

// ---------------------------------------------------------------------------
extern "C" void kernel_launch(void* const* d_in, const int* in_sizes, int n_in,
                              void* d_out, int out_size, void* d_ws, size_t ws_size,
                              hipStream_t stream) {
  (void)in_sizes; (void)n_in; (void)out_size; (void)ws_size;
  const float* x        = (const float*)d_in[0];
  const float* topic    = (const float*)d_in[1];
  const float* mask     = (const float*)d_in[2];
  const float* W_x2zr   = (const float*)d_in[3];
  const float* W_tp2zrx = (const float*)d_in[4];
  const float* W_xtp2z  = (const float*)d_in[5];
  const float* b_xtp2z  = (const float*)d_in[6];
  const float* W_xtp2r  = (const float*)d_in[7];
  const float* b_xtp2r  = (const float*)d_in[8];
  const float* W_h2zr   = (const float*)d_in[9];
  const float* W_tp2zrh = (const float*)d_in[10];
  const float* W_htp2z  = (const float*)d_in[11];
  const float* W_htp2r  = (const float*)d_in[12];
  const float* W_x2h    = (const float*)d_in[13];
  const float* W_tp2hx  = (const float*)d_in[14];
  const float* W_xtp2h  = (const float*)d_in[15];
  const float* b_xtp2h  = (const float*)d_in[16];
  const float* W_h2h    = (const float*)d_in[17];
  const float* W_tp2hh  = (const float*)d_in[18];
  const float* W_htp2h  = (const float*)d_in[19];
  float* out = (float*)d_out;

  // ---- workspace carve ----
  char* w = (char*)d_ws;
  int*            bar  = (int*)w;            w += 128;                        // barrier ctr
  float*          Hst  = (float*)w;          w += (size_t)BATCH * 512 * 4;    // 128 KB
  unsigned short* hbf  = (unsigned short*)w; w += (size_t)BATCH * 512 * 2;    // 64 KB
  // ^ [bar|Hst|hbf] contiguous: one memset zeroes all three.
  float* tzx = (float*)w;           w += (size_t)BATCH * 1024 * 4;
  float* tzh = (float*)w;           w += (size_t)BATCH * 1024 * 4;
  float* thx = (float*)w;           w += (size_t)BATCH * 512 * 4;
  float* thh = (float*)w;           w += (size_t)BATCH * 512 * 4;
  unsigned short* WaT = (unsigned short*)w;  w += (size_t)1536 * 512 * 2;     // 1.5 MB
  unsigned short* WbT = (unsigned short*)w;  w += (size_t)1536 * 512 * 2;     // 1.5 MB
  unsigned short* ZH  = (unsigned short*)w;  w += (size_t)BATCH * 1536 * 2;   // 192 KB
  unsigned short* ZRs   = (unsigned short*)w; w += (size_t)T_LEN * BATCH * 1024 * 2; // 64 MB
  unsigned short* ZRxtp = (unsigned short*)w; w += (size_t)T_LEN * BATCH * 1024 * 2; // 64 MB
  unsigned short* Xhs  = ZRs;                              // aliases (stream-ordered)
  unsigned short* Hxtp = ZRs + (size_t)T_LEN * BATCH * 512;

  const int M = T_LEN * BATCH;  // 32768

  hipMemsetAsync(bar, 0, 128 + (size_t)BATCH * 512 * 4 + (size_t)BATCH * 512 * 2, stream);

  // ---- weight transposes -> bf16 [n][k] ----
  k_tr<<<dim3(1024/32, 512/32), 256, 0, stream>>>(W_h2zr,  WaT,               512, 1024);
  k_tr<<<dim3( 512/32, 512/32), 256, 0, stream>>>(W_h2h,   WaT + 1024 * 512,  512,  512);
  k_tr<<<dim3( 512/32, 512/32), 256, 0, stream>>>(W_htp2z, WbT,               512,  512);
  k_tr<<<dim3( 512/32, 512/32), 256, 0, stream>>>(W_htp2r, WbT +  512 * 512,  512,  512);
  k_tr<<<dim3( 512/32, 512/32), 256, 0, stream>>>(W_htp2h, WbT + 1024 * 512,  512,  512);

  // ---- phase 1 ----
  k_topic<<<BATCH, 256, 0, stream>>>(topic, W_tp2zrx, W_tp2zrh, W_tp2hx, W_tp2hh,
                                     tzx, tzh, thx, thh);
  gemm64<0, true, true><<<dim3(1024/64, M/64), 256, 0, stream>>>(
      x, DIN, W_x2zr, 1024, tzx, 1024, nullptr, ZRs, 1024, DIN);
  gemm64<1, false, true><<<dim3(512/64, M/64), 256, 0, stream>>>(
      ZRs, 1024, W_xtp2z, 512, nullptr, 0, b_xtp2z, ZRxtp, 1024, 512);
  gemm64<1, false, true><<<dim3(512/64, M/64), 256, 0, stream>>>(
      ZRs + 512, 1024, W_xtp2r, 512, nullptr, 0, b_xtp2r, ZRxtp + 512, 1024, 512);
  gemm64<0, true, true><<<dim3(512/64, M/64), 256, 0, stream>>>(
      x, DIN, W_x2h, 512, thx, 512, nullptr, Xhs, 512, DIN);
  gemm64<1, false, true><<<dim3(512/64, M/64), 256, 0, stream>>>(
      Xhs, 512, W_xtp2h, 512, nullptr, 0, b_xtp2h, Hxtp, 512, 512);

  // ---- phase 2: persistent scan ----
  k_scan<<<G_WGS, 256, 0, stream>>>(WaT, WbT, tzh, thh, ZRxtp, Hxtp, mask,
                                    ZH, Hst, hbf, out, bar);
}